// Round 4
// baseline (311.004 us; speedup 1.0000x reference)
//
#include <hip/hip_runtime.h>

#define BLOCK 256

// ---------------------------------------------------------------------------
// Block-wide sum reduction: wave64 shuffle reduce, then LDS across waves.
// Returns the full block sum to ALL threads. Re-entrant (entry barrier).
// ---------------------------------------------------------------------------
__device__ __forceinline__ float block_reduce_sum(float v) {
    __shared__ float sm[BLOCK / 64];
    __syncthreads();
#pragma unroll
    for (int off = 32; off > 0; off >>= 1) v += __shfl_down(v, off, 64);
    const int lane = threadIdx.x & 63;
    const int wv = threadIdx.x >> 6;
    if (lane == 0) sm[wv] = v;
    __syncthreads();
    float s = sm[0];
#pragma unroll
    for (int i = 1; i < BLOCK / 64; ++i) s += sm[i];
    return s;
}

__device__ __forceinline__ float sq_sum4(float4 a, float4 b) {
    float dx = a.x - b.x, dy = a.y - b.y, dz = a.z - b.z, dw = a.w - b.w;
    return dx * dx + dy * dy + dz * dz + dw * dw;
}

// ---------------------------------------------------------------------------
// Per-element focal terms around K0:  u = m+K0, inv = rcp(u)
//   S += m ; A += m^3/u^2 ; B += m^3/u^3 ; C += m^3/u^4
// ---------------------------------------------------------------------------
__device__ __forceinline__ void focal_terms(float d, float K0, float& S,
                                            float& A, float& B, float& C) {
    float m = d * d;
    float u = m + K0;
    float inv = __builtin_amdgcn_rcpf(u);
    float m3 = m * m * m;
    float t2 = m3 * inv * inv;
    float t3 = t2 * inv;
    float t4 = t3 * inv;
    S += m; A += t2; B += t3; C += t4;
}

// ---------------------------------------------------------------------------
// Single fused kernel:
//  Phase 1: block-local K0_b from the block's first chunk (1024 elems, held
//           in registers — no re-read).
//  Phase 2: full grid-stride accumulation of S, A, B, C around K0_b.
//  Phase 3 (last finished block only): reduce partials -> K, apply per-block
//           2nd-order Taylor correction A_b - 2 B_b dK_b + 3 C_b dK_b^2,
//           domain-weight mean (int32/int64 sniff), write scalar.
// ---------------------------------------------------------------------------
__global__ void fused_all(const float4* __restrict__ p,
                          const float4* __restrict__ t,
                          float* __restrict__ pS, float* __restrict__ pA,
                          float* __restrict__ pB, float* __restrict__ pC,
                          float* __restrict__ pK0,
                          unsigned* __restrict__ cnt,
                          int n4, int ntail,
                          const float* __restrict__ tp,
                          const float* __restrict__ tt,
                          const int* __restrict__ dom32,
                          const long long* __restrict__ dom64, int Bn,
                          float inv_n, float* __restrict__ out) {
    const int step = gridDim.x * blockDim.x;
    const int i0 = blockIdx.x * blockDim.x + threadIdx.x;

    // ---- Phase 1: per-block K0 estimate from first chunk -------------------
    float4 a0, b0;
    const bool have0 = (i0 < n4);
    float lsum = 0.0f, lcnt = 0.0f;
    if (have0) {
        a0 = p[i0];
        b0 = t[i0];
        lsum = sq_sum4(a0, b0);
        lcnt = 4.0f;
    }
    float ssum = block_reduce_sum(lsum);
    float scnt = block_reduce_sum(lcnt);
    const float K0 = (scnt > 0.0f ? ssum / scnt : 0.0f) + 1e-8f;

    // ---- Phase 2: full accumulation around K0 ------------------------------
    float S = 0.0f, A = 0.0f, B = 0.0f, C = 0.0f;
    if (have0) {
        focal_terms(a0.x - b0.x, K0, S, A, B, C);
        focal_terms(a0.y - b0.y, K0, S, A, B, C);
        focal_terms(a0.z - b0.z, K0, S, A, B, C);
        focal_terms(a0.w - b0.w, K0, S, A, B, C);
    }
    for (int i = i0 + step; i < n4; i += step) {
        float4 a = p[i], b = t[i];
        focal_terms(a.x - b.x, K0, S, A, B, C);
        focal_terms(a.y - b.y, K0, S, A, B, C);
        focal_terms(a.z - b.z, K0, S, A, B, C);
        focal_terms(a.w - b.w, K0, S, A, B, C);
    }
    if (blockIdx.x == 0 && threadIdx.x == 0) {
        for (int k = 0; k < ntail; ++k)
            focal_terms(tp[k] - tt[k], K0, S, A, B, C);
    }
    S = block_reduce_sum(S);
    A = block_reduce_sum(A);
    B = block_reduce_sum(B);
    C = block_reduce_sum(C);

    __shared__ unsigned lastflag;
    if (threadIdx.x == 0) {
        pS[blockIdx.x] = S;
        pA[blockIdx.x] = A;
        pB[blockIdx.x] = B;
        pC[blockIdx.x] = C;
        pK0[blockIdx.x] = K0;
        __threadfence();                       // release partials
        unsigned old = atomicAdd(cnt, 1u);     // device-scope
        lastflag = (old == gridDim.x - 1) ? 1u : 0u;
    }
    __syncthreads();
    if (lastflag == 0u) return;
    __threadfence();                           // acquire partials

    // ---- Phase 3: final reduction (last block only) ------------------------
    const int nb = gridDim.x;
    float s = 0.0f;
    for (int i = threadIdx.x; i < nb; i += blockDim.x) s += pS[i];
    const float K = block_reduce_sum(s) * inv_n + 1e-8f;

    float fsum = 0.0f;
    for (int i = threadIdx.x; i < nb; i += blockDim.x) {
        float dK = K - pK0[i];
        fsum += pA[i] + dK * (-2.0f * pB[i] + 3.0f * pC[i] * dK);
    }
    fsum = block_reduce_sum(fsum);

    __shared__ int is32;
    if (threadIdx.x == 0) is32 = 0;
    __syncthreads();
    if (threadIdx.x < (unsigned)Bn) {
        int v = dom32[threadIdx.x];
        if ((threadIdx.x & 1) && v != 0) atomicOr(&is32, 1);
    }
    __syncthreads();
    float w = 0.0f;
    for (int i = threadIdx.x; i < Bn; i += blockDim.x) {
        int d = is32 ? dom32[i] : (int)dom64[i];
        w += (d == 0) ? 0.6502451783856802f
                      : ((d == 1) ? 1.449137674618944f : 2.509980079602226f);
    }
    float wt = block_reduce_sum(w);

    if (threadIdx.x == 0)
        out[0] = 0.25f * fsum * inv_n * (wt / (float)Bn);
}

extern "C" void kernel_launch(void* const* d_in, const int* in_sizes, int n_in,
                              void* d_out, int out_size, void* d_ws, size_t ws_size,
                              hipStream_t stream) {
    const float* pred = (const float*)d_in[0];
    const float* targ = (const float*)d_in[1];
    const int* dom32 = (const int*)d_in[2];
    const long long* dom64 = (const long long*)d_in[2];

    const int N = in_sizes[0];
    const int n4 = N >> 2;
    const int ntail = N & 3;
    const int Bn = in_sizes[2];
    const float inv_n = 1.0f / (float)N;

    int grid = 2048;  // 8 blocks/CU = full wave occupancy
    size_t avail = ws_size / sizeof(float);
    while ((size_t)(5 * grid + 4) > avail && grid > 1) grid >>= 1;

    float* ws = (float*)d_ws;
    float* pS = ws;
    float* pA = pS + grid;
    float* pB = pA + grid;
    float* pC = pB + grid;
    float* pK0 = pC + grid;
    unsigned* cnt = (unsigned*)(pK0 + grid);

    const float* tail_p = pred + (size_t)n4 * 4;
    const float* tail_t = targ + (size_t)n4 * 4;

    hipMemsetAsync(cnt, 0, sizeof(unsigned), stream);
    fused_all<<<grid, BLOCK, 0, stream>>>(
        (const float4*)pred, (const float4*)targ,
        pS, pA, pB, pC, pK0, cnt, n4, ntail, tail_p, tail_t,
        dom32, dom64, Bn, inv_n, (float*)d_out);
}

// Round 5
// 221.565 us; speedup vs baseline: 1.4037x; 1.4037x over previous
//
#include <hip/hip_runtime.h>

#define BLOCK 256

// ---------------------------------------------------------------------------
// Block-wide sum reduction: wave64 shuffle reduce, then LDS across waves.
// Returns the full block sum to ALL threads. Re-entrant (entry barrier).
// ---------------------------------------------------------------------------
__device__ __forceinline__ float block_reduce_sum(float v) {
    __shared__ float sm[BLOCK / 64];
    __syncthreads();
#pragma unroll
    for (int off = 32; off > 0; off >>= 1) v += __shfl_down(v, off, 64);
    const int lane = threadIdx.x & 63;
    const int wv = threadIdx.x >> 6;
    if (lane == 0) sm[wv] = v;
    __syncthreads();
    float s = sm[0];
#pragma unroll
    for (int i = 1; i < BLOCK / 64; ++i) s += sm[i];
    return s;
}

__device__ __forceinline__ float sq_sum4(float4 a, float4 b) {
    float dx = a.x - b.x, dy = a.y - b.y, dz = a.z - b.z, dw = a.w - b.w;
    return dx * dx + dy * dy + dz * dz + dw * dw;
}

// ---------------------------------------------------------------------------
// Per-element focal terms around K0:  u = m+K0, inv = rcp(u)
//   S += m ; A += m^3/u^2 ; B += m^3/u^3 ; C += m^3/u^4
// ---------------------------------------------------------------------------
__device__ __forceinline__ void focal_terms(float d, float K0, float& S,
                                            float& A, float& B, float& C) {
    float m = d * d;
    float u = m + K0;
    float inv = __builtin_amdgcn_rcpf(u);
    float m3 = m * m * m;
    float t2 = m3 * inv * inv;
    float t3 = t2 * inv;
    float t4 = t3 * inv;
    S += m; A += t2; B += t3; C += t4;
}

// ---------------------------------------------------------------------------
// Main pass (no atomics, no fences):
//  Prologue: block-local K0 from the block's first chunk (1024 elems). The
//  main loop re-reads that chunk from L1 — zero marginal HBM traffic, keeps
//  the hot loop byte-identical to the proven R3 shape.
//  Loop: grid-stride accumulation of S, A, B, C around K0_b.
// ---------------------------------------------------------------------------
__global__ void main_pass(const float4* __restrict__ p,
                          const float4* __restrict__ t,
                          float* __restrict__ pS, float* __restrict__ pA,
                          float* __restrict__ pB, float* __restrict__ pC,
                          float* __restrict__ pK0,
                          int n4, int ntail,
                          const float* __restrict__ tp,
                          const float* __restrict__ tt) {
    const int step = gridDim.x * blockDim.x;
    const int i0 = blockIdx.x * blockDim.x + threadIdx.x;

    // ---- block-local K0 estimate ------------------------------------------
    float lsum = 0.0f, lcnt = 0.0f;
    if (i0 < n4) {
        lsum = sq_sum4(p[i0], t[i0]);
        lcnt = 4.0f;
    }
    float ssum = block_reduce_sum(lsum);
    float scnt = block_reduce_sum(lcnt);
    const float K0 = (scnt > 0.0f ? ssum / scnt : 0.0f) + 1e-8f;

    // ---- full accumulation around K0 (R3-shape loop) ----------------------
    float S = 0.0f, A = 0.0f, B = 0.0f, C = 0.0f;
    for (int i = i0; i < n4; i += step) {
        float4 a = p[i], b = t[i];
        focal_terms(a.x - b.x, K0, S, A, B, C);
        focal_terms(a.y - b.y, K0, S, A, B, C);
        focal_terms(a.z - b.z, K0, S, A, B, C);
        focal_terms(a.w - b.w, K0, S, A, B, C);
    }
    if (blockIdx.x == 0 && threadIdx.x == 0) {
        for (int k = 0; k < ntail; ++k)
            focal_terms(tp[k] - tt[k], K0, S, A, B, C);
    }
    S = block_reduce_sum(S);
    A = block_reduce_sum(A);
    B = block_reduce_sum(B);
    C = block_reduce_sum(C);
    if (threadIdx.x == 0) {
        pS[blockIdx.x] = S;
        pA[blockIdx.x] = A;
        pB[blockIdx.x] = B;
        pC[blockIdx.x] = C;
        pK0[blockIdx.x] = K0;
    }
}

// ---------------------------------------------------------------------------
// Final: global K from exact S, per-block 2nd-order Taylor correction
//   f_b ~= A_b - 2 B_b dK_b + 3 C_b dK_b^2,   dK_b = K - K0_b
// then domain-weight mean (int32/int64 layout sniff: values 0..2 => int64
// high words all zero), scalar output.
// ---------------------------------------------------------------------------
__global__ void final_reduce(const float* __restrict__ pS,
                             const float* __restrict__ pA,
                             const float* __restrict__ pB,
                             const float* __restrict__ pC,
                             const float* __restrict__ pK0, int nb,
                             const int* __restrict__ dom32,
                             const long long* __restrict__ dom64, int Bn,
                             float inv_n, float* __restrict__ out) {
    float s = 0.0f;
    for (int i = threadIdx.x; i < nb; i += blockDim.x) s += pS[i];
    const float K = block_reduce_sum(s) * inv_n + 1e-8f;

    float fsum = 0.0f;
    for (int i = threadIdx.x; i < nb; i += blockDim.x) {
        float dK = K - pK0[i];
        fsum += pA[i] + dK * (-2.0f * pB[i] + 3.0f * pC[i] * dK);
    }
    fsum = block_reduce_sum(fsum);

    __shared__ int is32;
    if (threadIdx.x == 0) is32 = 0;
    __syncthreads();
    if (threadIdx.x < (unsigned)Bn) {
        int v = dom32[threadIdx.x];
        if ((threadIdx.x & 1) && v != 0) atomicOr(&is32, 1);
    }
    __syncthreads();
    float w = 0.0f;
    for (int i = threadIdx.x; i < Bn; i += blockDim.x) {
        int d = is32 ? dom32[i] : (int)dom64[i];
        w += (d == 0) ? 0.6502451783856802f
                      : ((d == 1) ? 1.449137674618944f : 2.509980079602226f);
    }
    float wt = block_reduce_sum(w);

    if (threadIdx.x == 0)
        out[0] = 0.25f * fsum * inv_n * (wt / (float)Bn);
}

extern "C" void kernel_launch(void* const* d_in, const int* in_sizes, int n_in,
                              void* d_out, int out_size, void* d_ws, size_t ws_size,
                              hipStream_t stream) {
    const float* pred = (const float*)d_in[0];
    const float* targ = (const float*)d_in[1];
    const int* dom32 = (const int*)d_in[2];
    const long long* dom64 = (const long long*)d_in[2];

    const int N = in_sizes[0];
    const int n4 = N >> 2;
    const int ntail = N & 3;
    const int Bn = in_sizes[2];
    const float inv_n = 1.0f / (float)N;

    int grid = 2048;  // 8 blocks/CU
    size_t avail = ws_size / sizeof(float);
    while ((size_t)(5 * grid) > avail && grid > 1) grid >>= 1;

    float* ws = (float*)d_ws;
    float* pS = ws;
    float* pA = pS + grid;
    float* pB = pA + grid;
    float* pC = pB + grid;
    float* pK0 = pC + grid;

    const float* tail_p = pred + (size_t)n4 * 4;
    const float* tail_t = targ + (size_t)n4 * 4;

    main_pass<<<grid, BLOCK, 0, stream>>>(
        (const float4*)pred, (const float4*)targ,
        pS, pA, pB, pC, pK0, n4, ntail, tail_p, tail_t);
    final_reduce<<<1, BLOCK, 0, stream>>>(
        pS, pA, pB, pC, pK0, grid, dom32, dom64, Bn, inv_n, (float*)d_out);
}

// Round 7
// 204.766 us; speedup vs baseline: 1.5188x; 1.0820x over previous
//
#include <hip/hip_runtime.h>

#define BLOCK 256

// clang native vector type — __builtin_nontemporal_load requires this
// (HIP_vector_type<float,4> is a struct and is rejected).
typedef float f4v __attribute__((ext_vector_type(4)));

// ---------------------------------------------------------------------------
// Block-wide sum reduction: wave64 shuffle reduce, then LDS across waves.
// Returns the full block sum to ALL threads. Re-entrant (entry barrier).
// ---------------------------------------------------------------------------
__device__ __forceinline__ float block_reduce_sum(float v) {
    __shared__ float sm[BLOCK / 64];
    __syncthreads();
#pragma unroll
    for (int off = 32; off > 0; off >>= 1) v += __shfl_down(v, off, 64);
    const int lane = threadIdx.x & 63;
    const int wv = threadIdx.x >> 6;
    if (lane == 0) sm[wv] = v;
    __syncthreads();
    float s = sm[0];
#pragma unroll
    for (int i = 1; i < BLOCK / 64; ++i) s += sm[i];
    return s;
}

__device__ __forceinline__ float sq_sum4(f4v a, f4v b) {
    float dx = a.x - b.x, dy = a.y - b.y, dz = a.z - b.z, dw = a.w - b.w;
    return dx * dx + dy * dy + dz * dz + dw * dw;
}

// ---------------------------------------------------------------------------
// Per-element focal terms around K0:  u = m+K0, inv = rcp(u)
//   S += m ; A += m^3/u^2 ; B += m^3/u^3 ; C += m^3/u^4
// ---------------------------------------------------------------------------
__device__ __forceinline__ void focal_terms(float d, float K0, float& S,
                                            float& A, float& B, float& C) {
    float m = d * d;
    float u = m + K0;
    float inv = __builtin_amdgcn_rcpf(u);
    float m3 = m * m * m;
    float t2 = m3 * inv * inv;
    float t3 = t2 * inv;
    float t4 = t3 * inv;
    S += m; A += t2; B += t3; C += t4;
}

// ---------------------------------------------------------------------------
// Main pass, R6 experiment (type-fixed): per-block CONTIGUOUS chunks +
// NONTEMPORAL loads.
//  - nt loads bypass L2/L3 allocation: tests whether the mixed L3-hit path
//    was throttling reads to ~2.6 TB/s (R5) vs pure HBM streaming.
//  - contiguous per-CU address streams maximize HBM row-buffer locality.
//  Prologue: block-local K0 from the chunk's first 1024 elems via NORMAL
//  (cached) loads, so the main loop's iteration 0 re-read hits L1.
// ---------------------------------------------------------------------------
__global__ void main_pass(const f4v* __restrict__ p,
                          const f4v* __restrict__ t,
                          float* __restrict__ pS, float* __restrict__ pA,
                          float* __restrict__ pB, float* __restrict__ pC,
                          float* __restrict__ pK0,
                          int n4, int iters, int ntail,
                          const float* __restrict__ tp,
                          const float* __restrict__ tt) {
    const int chunk = iters * BLOCK;
    const int start = blockIdx.x * chunk;
    const int i0 = start + threadIdx.x;
    int end = start + chunk;
    if (end > n4) end = n4;

    // ---- block-local K0 estimate (cached loads) ---------------------------
    float lsum = 0.0f, lcnt = 0.0f;
    if (i0 < n4) {
        lsum = sq_sum4(p[i0], t[i0]);
        lcnt = 4.0f;
    }
    float ssum = block_reduce_sum(lsum);
    float scnt = block_reduce_sum(lcnt);
    const float K0 = (scnt > 0.0f ? ssum / scnt : 0.0f) + 1e-8f;

    // ---- full accumulation around K0, nontemporal streaming ---------------
    float S = 0.0f, A = 0.0f, B = 0.0f, C = 0.0f;
    for (int i = i0; i < end; i += BLOCK) {
        f4v a = __builtin_nontemporal_load(p + i);
        f4v b = __builtin_nontemporal_load(t + i);
        focal_terms(a.x - b.x, K0, S, A, B, C);
        focal_terms(a.y - b.y, K0, S, A, B, C);
        focal_terms(a.z - b.z, K0, S, A, B, C);
        focal_terms(a.w - b.w, K0, S, A, B, C);
    }
    if (blockIdx.x == 0 && threadIdx.x == 0) {
        for (int k = 0; k < ntail; ++k)
            focal_terms(tp[k] - tt[k], K0, S, A, B, C);
    }
    S = block_reduce_sum(S);
    A = block_reduce_sum(A);
    B = block_reduce_sum(B);
    C = block_reduce_sum(C);
    if (threadIdx.x == 0) {
        pS[blockIdx.x] = S;
        pA[blockIdx.x] = A;
        pB[blockIdx.x] = B;
        pC[blockIdx.x] = C;
        pK0[blockIdx.x] = K0;
    }
}

// ---------------------------------------------------------------------------
// Final: global K from exact S, per-block 2nd-order Taylor correction
//   f_b ~= A_b - 2 B_b dK_b + 3 C_b dK_b^2,   dK_b = K - K0_b
// then domain-weight mean (int32/int64 layout sniff: values 0..2 => int64
// high words all zero), scalar output.
// ---------------------------------------------------------------------------
__global__ void final_reduce(const float* __restrict__ pS,
                             const float* __restrict__ pA,
                             const float* __restrict__ pB,
                             const float* __restrict__ pC,
                             const float* __restrict__ pK0, int nb,
                             const int* __restrict__ dom32,
                             const long long* __restrict__ dom64, int Bn,
                             float inv_n, float* __restrict__ out) {
    float s = 0.0f;
    for (int i = threadIdx.x; i < nb; i += blockDim.x) s += pS[i];
    const float K = block_reduce_sum(s) * inv_n + 1e-8f;

    float fsum = 0.0f;
    for (int i = threadIdx.x; i < nb; i += blockDim.x) {
        float dK = K - pK0[i];
        fsum += pA[i] + dK * (-2.0f * pB[i] + 3.0f * pC[i] * dK);
    }
    fsum = block_reduce_sum(fsum);

    __shared__ int is32;
    if (threadIdx.x == 0) is32 = 0;
    __syncthreads();
    if (threadIdx.x < (unsigned)Bn) {
        int v = dom32[threadIdx.x];
        if ((threadIdx.x & 1) && v != 0) atomicOr(&is32, 1);
    }
    __syncthreads();
    float w = 0.0f;
    for (int i = threadIdx.x; i < Bn; i += blockDim.x) {
        int d = is32 ? dom32[i] : (int)dom64[i];
        w += (d == 0) ? 0.6502451783856802f
                      : ((d == 1) ? 1.449137674618944f : 2.509980079602226f);
    }
    float wt = block_reduce_sum(w);

    if (threadIdx.x == 0)
        out[0] = 0.25f * fsum * inv_n * (wt / (float)Bn);
}

extern "C" void kernel_launch(void* const* d_in, const int* in_sizes, int n_in,
                              void* d_out, int out_size, void* d_ws, size_t ws_size,
                              hipStream_t stream) {
    const float* pred = (const float*)d_in[0];
    const float* targ = (const float*)d_in[1];
    const int* dom32 = (const int*)d_in[2];
    const long long* dom64 = (const long long*)d_in[2];

    const int N = in_sizes[0];
    const int n4 = N >> 2;
    const int ntail = N & 3;
    const int Bn = in_sizes[2];
    const float inv_n = 1.0f / (float)N;

    int grid = 2048;  // 8 blocks/CU
    size_t avail = ws_size / sizeof(float);
    while ((size_t)(5 * grid) > avail && grid > 1) grid >>= 1;

    // contiguous chunk per block, whole-block iterations
    const int iters = (n4 + grid * BLOCK - 1) / (grid * BLOCK);

    float* ws = (float*)d_ws;
    float* pS = ws;
    float* pA = pS + grid;
    float* pB = pA + grid;
    float* pC = pB + grid;
    float* pK0 = pC + grid;

    const float* tail_p = pred + (size_t)n4 * 4;
    const float* tail_t = targ + (size_t)n4 * 4;

    main_pass<<<grid, BLOCK, 0, stream>>>(
        (const f4v*)pred, (const f4v*)targ,
        pS, pA, pB, pC, pK0, n4, iters, ntail, tail_p, tail_t);
    final_reduce<<<1, BLOCK, 0, stream>>>(
        pS, pA, pB, pC, pK0, grid, dom32, dom64, Bn, inv_n, (float*)d_out);
}